// Round 5
// baseline (1125.356 us; speedup 1.0000x reference)
//
#include <hip/hip_runtime.h>

#define TE 64      // edges per tile (kernel A)
#define TN 64      // nodes per tile (kernel B)

union F4 { float4 v; float f[4]; };

__device__ __forceinline__ float gelu_f(float x) {
    // jax.nn.gelu(approximate=True): 0.5*x*(1+tanh(sqrt(2/pi)*(x+0.044715*x^3)))
    const float c0 = 0.7978845608028654f;
    float z = c0 * (x + 0.044715f * x * x * x);
    float ez = __builtin_exp2f(z * 2.8853900817779268f);
    float th = 1.0f - 2.0f * __builtin_amdgcn_rcpf(ez + 1.0f);
    return 0.5f * x * (1.0f + th);
}

// barrier that does NOT drain vmcnt: own-wave LDS ops drained (lgkmcnt),
// global stores/atomics stay in flight across tiles.
__device__ __forceinline__ void barrier_lgkm() {
    asm volatile("s_waitcnt lgkmcnt(0)" ::: "memory");
    __builtin_amdgcn_s_barrier();
}

// ---------------- Kernel A: edge MLP ----------------
// msg2 != nullptr: store per-edge result rows (CSR/gather path, no atomics).
// msg2 == nullptr: atomic scatter-add into agg (fallback path).
__global__ __launch_bounds__(256, 4) void edge_mlp_kernel(
    const float* __restrict__ nf,   // [N,64]
    const float* __restrict__ ef,   // [E,16]
    const int*   __restrict__ ei,   // [2,E] int32
    const float* __restrict__ W1,   // [80,64]
    const float* __restrict__ b1,   // [64]
    const float* __restrict__ W2,   // [64,64]
    const float* __restrict__ b2,   // [64]
    float*       agg,               // [N,64] (fallback only, pre-zeroed)
    float*       msg2,              // [E,64] or null
    int nE, int nTiles)
{
    __shared__ float sX[80][TE + 4];   // x transposed: [k][e]
    __shared__ float sM[64][TE + 4];   // gelu(msg1) transposed: [c][e]
    __shared__ int   sDst[TE];

    const int t    = threadIdx.x;
    const int lane = t & 63;
    const int w    = t >> 6;          // wave id 0..3
    const int e0   = (t & 15) * 4;    // microtile edges
    const int c0   = (t >> 4) * 4;    // microtile channels
    F4 b1v, b2v;
    b1v.v = *(const float4*)(b1 + c0);
    b2v.v = *(const float4*)(b2 + c0);

    for (int tile = blockIdx.x; tile < nTiles; tile += gridDim.x) {
        const int gbase = tile * TE;
        // ---- gather: edge (=lane) x feature-chunk (=wave) ----
        {
            int ge = gbase + lane;
            if (ge >= nE) ge = nE - 1;              // clamp (tail-safe)
            const int src = ei[ge];
            const float4* nrow = (const float4*)(nf + (size_t)src * 64);
            F4 a0, a1, a2, a3, ev;
            a0.v = nrow[w * 4 + 0];
            a1.v = nrow[w * 4 + 1];
            a2.v = nrow[w * 4 + 2];
            a3.v = nrow[w * 4 + 3];
            ev.v = *(const float4*)(ef + (size_t)ge * 16 + w * 4);
            const int kb = w * 16;
            #pragma unroll
            for (int j = 0; j < 4; ++j) {
                sX[kb + 0  + j][lane] = a0.f[j];
                sX[kb + 4  + j][lane] = a1.f[j];
                sX[kb + 8  + j][lane] = a2.f[j];
                sX[kb + 12 + j][lane] = a3.f[j];
                sX[64 + w * 4 + j][lane] = ev.f[j];
            }
            if (!msg2 && w == 0) sDst[lane] = ei[nE + ge];
        }
        barrier_lgkm();

        // ---- GEMM1: [64e x 80] @ [80 x 64c], W1 streamed from L1 ----
        float acc[4][4] = {};
        #pragma unroll 8
        for (int k = 0; k < 80; ++k) {
            F4 xv, wv;
            xv.v = *(const float4*)&sX[k][e0];
            wv.v = *(const float4*)(W1 + k * 64 + c0);
            #pragma unroll
            for (int i = 0; i < 4; ++i)
                #pragma unroll
                for (int j = 0; j < 4; ++j)
                    acc[i][j] = fmaf(xv.f[i], wv.f[j], acc[i][j]);
        }
        // gelu + write transposed msg1
        #pragma unroll
        for (int j = 0; j < 4; ++j) {
            F4 col;
            #pragma unroll
            for (int i = 0; i < 4; ++i)
                col.f[i] = gelu_f(acc[i][j] + b1v.f[j]);
            *(float4*)&sM[c0 + j][e0] = col.v;
        }
        barrier_lgkm();

        // ---- GEMM2: [64e x 64] @ [64 x 64c], W2 streamed from L1 ----
        float acc2[4][4] = {};
        #pragma unroll 8
        for (int k = 0; k < 64; ++k) {
            F4 xv, wv;
            xv.v = *(const float4*)&sM[k][e0];
            wv.v = *(const float4*)(W2 + k * 64 + c0);
            #pragma unroll
            for (int i = 0; i < 4; ++i)
                #pragma unroll
                for (int j = 0; j < 4; ++j)
                    acc2[i][j] = fmaf(xv.f[i], wv.f[j], acc2[i][j]);
        }

        if (msg2) {
            // ---- plain stores of per-edge rows (no atomics) ----
            #pragma unroll
            for (int i = 0; i < 4; ++i) {
                const int ge = gbase + e0 + i;
                if (ge < nE) {
                    F4 o;
                    #pragma unroll
                    for (int j = 0; j < 4; ++j) o.f[j] = acc2[i][j] + b2v.f[j];
                    *(float4*)(msg2 + (size_t)ge * 64 + c0) = o.v;
                }
            }
            // no end-of-loop barrier needed: barriers 1+2 already fence sX/sM reuse
        } else {
            // ---- fallback: atomic scatter-add ----
            #pragma unroll
            for (int i = 0; i < 4; ++i) {
                if (gbase + e0 + i < nE) {
                    float* arow = agg + (size_t)sDst[e0 + i] * 64 + c0;
                    #pragma unroll
                    for (int j = 0; j < 4; ++j)
                        __hip_atomic_fetch_add(arow + j, acc2[i][j] + b2v.f[j],
                                               __ATOMIC_RELAXED, __HIP_MEMORY_SCOPE_AGENT);
                }
            }
            barrier_lgkm();   // protect sDst for next tile
        }
    }
}

// ---------------- CSR build ----------------
__global__ __launch_bounds__(256) void hist_kernel(const int* __restrict__ dst,
                                                   int* __restrict__ counts, int nE) {
    int e = blockIdx.x * 256 + threadIdx.x;
    const int stride = gridDim.x * 256;
    for (; e < nE; e += stride)
        atomicAdd(&counts[dst[e]], 1);
}

// block-local exclusive scan: 256 thr x 8 elems = 2048/block
__global__ __launch_bounds__(256) void scan_local_kernel(const int* __restrict__ in,
                                                         int* __restrict__ out,
                                                         int* __restrict__ bsum, int n) {
    __shared__ int s[256];
    const int t = threadIdx.x;
    const int base = blockIdx.x * 2048 + t * 8;
    int v[8];
    #pragma unroll
    for (int i = 0; i < 8; ++i) v[i] = (base + i < n) ? in[base + i] : 0;
    int run = 0;
    #pragma unroll
    for (int i = 0; i < 8; ++i) { int c = v[i]; v[i] = run; run += c; }
    s[t] = run;
    __syncthreads();
    int x = run;
    for (int off = 1; off < 256; off <<= 1) {
        int y = (t >= off) ? s[t - off] : 0;
        __syncthreads();
        x += y; s[t] = x;
        __syncthreads();
    }
    const int texcl = x - run;
    if (t == 255) bsum[blockIdx.x] = x;
    #pragma unroll
    for (int i = 0; i < 8; ++i)
        if (base + i < n) out[base + i] = texcl + v[i];
}

__global__ void scan_bsums_kernel(int* bsum, int nb) {
    if (threadIdx.x == 0 && blockIdx.x == 0) {
        int run = 0;
        for (int b = 0; b < nb; ++b) { int tt = bsum[b]; bsum[b] = run; run += tt; }
    }
}

__global__ __launch_bounds__(256) void scan_add_kernel(int* __restrict__ offs,
                                                       const int* __restrict__ bsum,
                                                       int* __restrict__ cursor, int n) {
    const int base = blockIdx.x * 2048 + threadIdx.x * 8;
    const int add = bsum[blockIdx.x];
    #pragma unroll
    for (int i = 0; i < 8; ++i)
        if (base + i < n) { int v = offs[base + i] + add; offs[base + i] = v; cursor[base + i] = v; }
}

__global__ __launch_bounds__(256) void scatter_kernel(const int* __restrict__ dst,
                                                      int* __restrict__ cursor,
                                                      int* __restrict__ eids, int nE) {
    int e = blockIdx.x * 256 + threadIdx.x;
    const int stride = gridDim.x * 256;
    for (; e < nE; e += stride) {
        const int d = dst[e];
        const int pos = atomicAdd(&cursor[d], 1);
        eids[pos] = e;
    }
}

// ---------------- gather-aggregate: one wave per node ----------------
__global__ __launch_bounds__(256) void agg_kernel(const float* __restrict__ msg2,
                                                  const int* __restrict__ offs,
                                                  const int* __restrict__ counts,
                                                  const int* __restrict__ eids,
                                                  float* __restrict__ agg, int nN) {
    const int lane = threadIdx.x & 63;
    const int n = blockIdx.x * 4 + (threadIdx.x >> 6);
    if (n >= nN) return;
    const int start = offs[n];
    const int cnt   = counts[n];
    float acc = 0.f;
    int i = 0;
    for (; i + 2 <= cnt; i += 2) {
        const int ea = eids[start + i];
        const int eb = eids[start + i + 1];
        const float a = msg2[(size_t)ea * 64 + lane];
        const float b = msg2[(size_t)eb * 64 + lane];
        acc += a; acc += b;
    }
    if (i < cnt) acc += msg2[(size_t)eids[start + i] * 64 + lane];
    agg[(size_t)n * 64 + lane] = acc;
}

// ---------------- Kernel B: node update + LayerNorm + GELU + residual ----------------
__global__ __launch_bounds__(256) void node_update_kernel(
    const float* __restrict__ nf,   // [N,64]
    const float* agg,               // [N,64] (may alias out in fallback)
    const float* __restrict__ W3,   // [128,64]
    const float* __restrict__ b3,   // [64]
    const float* __restrict__ lns,  // [64]
    const float* __restrict__ lnb,  // [64]
    float* out, int nN)
{
    __shared__ float sW3[128][64];
    __shared__ float sU[128][TN + 4];   // upd transposed [k][n]
    __shared__ float sP1[16][TN];
    __shared__ float sP2[16][TN];
    __shared__ float sMu[TN];
    __shared__ float sRs[TN];

    const int t = threadIdx.x;
    for (int i = t * 4; i < 128 * 64; i += 1024)
        *(float4*)((float*)sW3 + i) = *(const float4*)(W3 + i);

    const int lane = t & 63;
    const int w    = t >> 6;
    const int tb   = blockIdx.x * TN;
    const int node = tb + lane;
    const bool valid = node < nN;

    {
        const float* base = (w < 2) ? (nf  + (size_t)node * 64 + w * 32)
                                    : (agg + (size_t)node * 64 + (w - 2) * 32);
        const int kb = (w < 2) ? (w * 32) : (64 + (w - 2) * 32);
        #pragma unroll
        for (int q = 0; q < 8; ++q) {
            F4 v;
            v.v = valid ? *(const float4*)(base + q * 4) : make_float4(0.f, 0.f, 0.f, 0.f);
            #pragma unroll
            for (int j = 0; j < 4; ++j)
                sU[kb + q * 4 + j][lane] = v.f[j];
        }
    }

    const int n0 = (t & 15) * 4;
    const int c0 = (t >> 4) * 4;
    F4 b3v, sv, bv;
    b3v.v = *(const float4*)(b3  + c0);
    sv.v  = *(const float4*)(lns + c0);
    bv.v  = *(const float4*)(lnb + c0);
    __syncthreads();

    float acc[4][4] = {};
    #pragma unroll 8
    for (int k = 0; k < 128; ++k) {
        F4 xv, wv;
        xv.v = *(const float4*)&sU[k][n0];
        wv.v = *(const float4*)&sW3[k][c0];
        #pragma unroll
        for (int i = 0; i < 4; ++i)
            #pragma unroll
            for (int j = 0; j < 4; ++j)
                acc[i][j] = fmaf(xv.f[i], wv.f[j], acc[i][j]);
    }

    float h[4][4];
    #pragma unroll
    for (int i = 0; i < 4; ++i)
        #pragma unroll
        for (int j = 0; j < 4; ++j)
            h[i][j] = acc[i][j] + b3v.f[j];

    const int cg = t >> 4;
    #pragma unroll
    for (int i = 0; i < 4; ++i) {
        float s1 = h[i][0] + h[i][1] + h[i][2] + h[i][3];
        float s2 = h[i][0]*h[i][0] + h[i][1]*h[i][1] + h[i][2]*h[i][2] + h[i][3]*h[i][3];
        sP1[cg][n0 + i] = s1;
        sP2[cg][n0 + i] = s2;
    }
    __syncthreads();
    if (t < TN) {
        float m1 = 0.f, m2 = 0.f;
        #pragma unroll
        for (int g = 0; g < 16; ++g) { m1 += sP1[g][t]; m2 += sP2[g][t]; }
        float mu  = m1 * (1.f / 64.f);
        float var = m2 * (1.f / 64.f) - mu * mu;
        sMu[t] = mu;
        sRs[t] = rsqrtf(var + 1e-6f);
    }
    __syncthreads();

    #pragma unroll
    for (int i = 0; i < 4; ++i) {
        const int gnode = tb + n0 + i;
        const float mu = sMu[n0 + i];
        const float rs = sRs[n0 + i];
        if (gnode < nN) {
            #pragma unroll
            for (int j = 0; j < 4; ++j) {
                float xn = (h[i][j] - mu) * rs * sv.f[j] + bv.f[j];
                float r  = gelu_f(xn) + sU[c0 + j][n0 + i];
                out[(size_t)gnode * 64 + c0 + j] = r;
            }
        }
    }
}

extern "C" void kernel_launch(void* const* d_in, const int* in_sizes, int n_in,
                              void* d_out, int out_size, void* d_ws, size_t ws_size,
                              hipStream_t stream)
{
    const float* nf  = (const float*)d_in[0];
    const float* ef  = (const float*)d_in[1];
    const int*   ei  = (const int*)  d_in[2];
    const float* W1  = (const float*)d_in[3];
    const float* b1  = (const float*)d_in[4];
    const float* W2  = (const float*)d_in[5];
    const float* b2  = (const float*)d_in[6];
    const float* W3  = (const float*)d_in[7];
    const float* b3  = (const float*)d_in[8];
    const float* lns = (const float*)d_in[9];
    const float* lnb = (const float*)d_in[10];

    const int nN = in_sizes[0] / 64;
    const int nE = in_sizes[2] / 2;
    float* out = (float*)d_out;
    const int* dstArr = ei + nE;

    const int nTiles = (nE + TE - 1) / TE;
    const int gridA  = nTiles < 1024 ? nTiles : 1024;
    const int gridB  = (nN + TN - 1) / TN;

    // ws layout (all offsets multiples of 16B)
    char* ws = (char*)d_ws;
    size_t off = 0;
    float* msg2   = (float*)(ws + off); off += (size_t)nE * 64 * 4;
    int*   counts = (int*)  (ws + off); off += (size_t)nN * 4;
    int*   offs   = (int*)  (ws + off); off += (size_t)nN * 4;
    int*   cursor = (int*)  (ws + off); off += (size_t)nN * 4;
    int*   bsum   = (int*)  (ws + off); off += 4096;
    int*   eids   = (int*)  (ws + off); off += (size_t)nE * 4;
    float* agg    = (float*)(ws + off); off += (size_t)nN * 64 * 4;
    const bool fast = (ws_size >= off) && (((size_t)nN * 4) % 16 == 0);

    if (fast) {
        const int nb = (nN + 2047) / 2048;
        hipMemsetAsync(counts, 0, (size_t)nN * 4, stream);
        hipLaunchKernelGGL(hist_kernel, dim3(2048), dim3(256), 0, stream, dstArr, counts, nE);
        hipLaunchKernelGGL(scan_local_kernel, dim3(nb), dim3(256), 0, stream, counts, offs, bsum, nN);
        hipLaunchKernelGGL(scan_bsums_kernel, dim3(1), dim3(64), 0, stream, bsum, nb);
        hipLaunchKernelGGL(scan_add_kernel, dim3(nb), dim3(256), 0, stream, offs, bsum, cursor, nN);
        hipLaunchKernelGGL(scatter_kernel, dim3(2048), dim3(256), 0, stream, dstArr, cursor, eids, nE);
        hipLaunchKernelGGL(edge_mlp_kernel, dim3(gridA), dim3(256), 0, stream,
                           nf, ef, ei, W1, b1, W2, b2, (float*)nullptr, msg2, nE, nTiles);
        hipLaunchKernelGGL(agg_kernel, dim3((nN + 3) / 4), dim3(256), 0, stream,
                           msg2, offs, counts, eids, agg, nN);
        hipLaunchKernelGGL(node_update_kernel, dim3(gridB), dim3(256), 0, stream,
                           nf, agg, W3, b3, lns, lnb, out, nN);
    } else {
        const size_t aggBytes = (size_t)nN * 64 * sizeof(float);
        float* agg2 = (ws_size >= aggBytes) ? (float*)d_ws : out;
        hipMemsetAsync(agg2, 0, aggBytes, stream);
        hipLaunchKernelGGL(edge_mlp_kernel, dim3(gridA), dim3(256), 0, stream,
                           nf, ef, ei, W1, b1, W2, b2, agg2, (float*)nullptr, nE, nTiles);
        hipLaunchKernelGGL(node_update_kernel, dim3(gridB), dim3(256), 0, stream,
                           nf, agg2, W3, b3, lns, lnb, out, nN);
    }
}

// Round 6
// 688.054 us; speedup vs baseline: 1.6356x; 1.6356x over previous
//
#include <hip/hip_runtime.h>

#define TE 64      // edges per tile (kernel A)
#define TN 64      // nodes per tile (kernel B)

union F4 { float4 v; float f[4]; };

__device__ __forceinline__ float gelu_f(float x) {
    // jax.nn.gelu(approximate=True): 0.5*x*(1+tanh(sqrt(2/pi)*(x+0.044715*x^3)))
    const float c0 = 0.7978845608028654f;
    float z = c0 * (x + 0.044715f * x * x * x);
    float ez = __builtin_exp2f(z * 2.8853900817779268f);
    float th = 1.0f - 2.0f * __builtin_amdgcn_rcpf(ez + 1.0f);
    return 0.5f * x * (1.0f + th);
}

// barrier that does NOT drain vmcnt: own-wave LDS ops drained (lgkmcnt),
// global stores/atomics stay in flight across tiles.
__device__ __forceinline__ void barrier_lgkm() {
    asm volatile("s_waitcnt lgkmcnt(0)" ::: "memory");
    __builtin_amdgcn_s_barrier();
}

// ---------------- Kernel A: edge MLP ----------------
// eids != null: edges processed in dst-sorted order; per-tile segmented
//               reduction -> ~E/11 atomics instead of E*64.
// eids == null: atomic scatter-add per edge (fallback).
__global__ __launch_bounds__(256, 4) void edge_mlp_kernel(
    const float* __restrict__ nf,   // [N,64]
    const float* __restrict__ ef,   // [E,16]
    const int*   __restrict__ ei,   // [2,E] int32
    const int*   __restrict__ eids, // [E] sorted-by-dst edge ids, or null
    const int2*  __restrict__ sd,   // [E] {src,dst} in sorted order, or null
    const float* __restrict__ W1,   // [80,64]
    const float* __restrict__ b1,   // [64]
    const float* __restrict__ W2,   // [64,64]
    const float* __restrict__ b2,   // [64]
    float*       agg,               // [N,64] (pre-zeroed)
    int nE, int nTiles)
{
    __shared__ float sX[80][TE + 4];   // x transposed [k][e]; rows 0..63 reused for results
    __shared__ float sM[64][TE + 4];   // gelu(msg1) transposed [c][e]
    __shared__ int   sDst[TE];

    const int t    = threadIdx.x;
    const int lane = t & 63;
    const int w    = t >> 6;          // wave id 0..3
    const int e0   = (t & 15) * 4;    // microtile edges
    const int c0   = (t >> 4) * 4;    // microtile channels
    const bool sorted = (eids != nullptr);
    F4 b1v, b2v;
    b1v.v = *(const float4*)(b1 + c0);
    b2v.v = *(const float4*)(b2 + c0);

    for (int tile = blockIdx.x; tile < nTiles; tile += gridDim.x) {
        const int gbase = tile * TE;
        // ---- gather: edge (=lane) x feature-chunk (=wave) ----
        {
            const int idx = gbase + lane;
            int ge, src, dstv;
            if (sorted) {
                const int ci = idx < nE ? idx : nE - 1;     // clamp (tail-safe)
                ge = eids[ci];
                const int2 p = sd[ci];
                src  = p.x;
                dstv = (idx < nE) ? p.y : -1;               // sentinel for pad edges
            } else {
                ge   = idx < nE ? idx : nE - 1;
                src  = ei[ge];
                dstv = (idx < nE) ? ei[nE + ge] : -1;
            }
            const float4* nrow = (const float4*)(nf + (size_t)src * 64);
            F4 a0, a1, a2, a3, ev;
            a0.v = nrow[w * 4 + 0];
            a1.v = nrow[w * 4 + 1];
            a2.v = nrow[w * 4 + 2];
            a3.v = nrow[w * 4 + 3];
            ev.v = *(const float4*)(ef + (size_t)ge * 16 + w * 4);
            const int kb = w * 16;
            #pragma unroll
            for (int j = 0; j < 4; ++j) {
                sX[kb + 0  + j][lane] = a0.f[j];
                sX[kb + 4  + j][lane] = a1.f[j];
                sX[kb + 8  + j][lane] = a2.f[j];
                sX[kb + 12 + j][lane] = a3.f[j];
                sX[64 + w * 4 + j][lane] = ev.f[j];
            }
            if (w == 0) sDst[lane] = dstv;
        }
        barrier_lgkm();

        // ---- GEMM1: [64e x 80] @ [80 x 64c], W1 streamed from L1 ----
        float acc[4][4] = {};
        #pragma unroll 8
        for (int k = 0; k < 80; ++k) {
            F4 xv, wv;
            xv.v = *(const float4*)&sX[k][e0];
            wv.v = *(const float4*)(W1 + k * 64 + c0);
            #pragma unroll
            for (int i = 0; i < 4; ++i)
                #pragma unroll
                for (int j = 0; j < 4; ++j)
                    acc[i][j] = fmaf(xv.f[i], wv.f[j], acc[i][j]);
        }
        // gelu + write transposed msg1
        #pragma unroll
        for (int j = 0; j < 4; ++j) {
            F4 col;
            #pragma unroll
            for (int i = 0; i < 4; ++i)
                col.f[i] = gelu_f(acc[i][j] + b1v.f[j]);
            *(float4*)&sM[c0 + j][e0] = col.v;
        }
        barrier_lgkm();

        // ---- GEMM2: [64e x 64] @ [64 x 64c], W2 streamed from L1 ----
        float acc2[4][4] = {};
        #pragma unroll 8
        for (int k = 0; k < 64; ++k) {
            F4 xv, wv;
            xv.v = *(const float4*)&sM[k][e0];
            wv.v = *(const float4*)(W2 + k * 64 + c0);
            #pragma unroll
            for (int i = 0; i < 4; ++i)
                #pragma unroll
                for (int j = 0; j < 4; ++j)
                    acc2[i][j] = fmaf(xv.f[i], wv.f[j], acc2[i][j]);
        }

        if (sorted) {
            // write results transposed into sX rows 0..63 (dead after GEMM1)
            #pragma unroll
            for (int j = 0; j < 4; ++j) {
                F4 col;
                #pragma unroll
                for (int i = 0; i < 4; ++i)
                    col.f[i] = acc2[i][j] + b2v.f[j];
                *(float4*)&sX[c0 + j][e0] = col.v;
            }
            barrier_lgkm();

            // ---- segmented reduction along sorted-edge axis ----
            // thread = channel c (0..63) x chunk q (16 edges each)
            const int c = t >> 2;
            const int q = t & 3;
            const int cb = q * 16;
            int   cur = sDst[cb];
            float run = (cur >= 0) ? sX[c][cb] : 0.f;
            #pragma unroll
            for (int i = 1; i < 16; ++i) {
                const int d = sDst[cb + i];
                const float v = (d >= 0) ? sX[c][cb + i] : 0.f;
                if (d == cur) {
                    run += v;
                } else {
                    if (cur >= 0)
                        __hip_atomic_fetch_add(agg + (size_t)cur * 64 + c, run,
                                               __ATOMIC_RELAXED, __HIP_MEMORY_SCOPE_AGENT);
                    cur = d;
                    run = v;
                }
            }
            if (cur >= 0)
                __hip_atomic_fetch_add(agg + (size_t)cur * 64 + c, run,
                                       __ATOMIC_RELAXED, __HIP_MEMORY_SCOPE_AGENT);
            barrier_lgkm();   // protect sX/sDst before next tile's gather
        } else {
            // ---- fallback: atomic scatter-add per edge ----
            #pragma unroll
            for (int i = 0; i < 4; ++i) {
                if (gbase + e0 + i < nE) {
                    float* arow = agg + (size_t)sDst[e0 + i] * 64 + c0;
                    #pragma unroll
                    for (int j = 0; j < 4; ++j)
                        __hip_atomic_fetch_add(arow + j, acc2[i][j] + b2v.f[j],
                                               __ATOMIC_RELAXED, __HIP_MEMORY_SCOPE_AGENT);
                }
            }
            barrier_lgkm();   // protect sDst for next tile
        }
    }
}

// ---------------- CSR build ----------------
__global__ __launch_bounds__(256) void hist_kernel(const int* __restrict__ dst,
                                                   int* __restrict__ counts, int nE) {
    int e = blockIdx.x * 256 + threadIdx.x;
    const int stride = gridDim.x * 256;
    for (; e < nE; e += stride)
        atomicAdd(&counts[dst[e]], 1);
}

// block-local exclusive scan: 256 thr x 8 elems = 2048/block
__global__ __launch_bounds__(256) void scan_local_kernel(const int* __restrict__ in,
                                                         int* __restrict__ out,
                                                         int* __restrict__ bsum, int n) {
    __shared__ int s[256];
    const int t = threadIdx.x;
    const int base = blockIdx.x * 2048 + t * 8;
    int v[8];
    #pragma unroll
    for (int i = 0; i < 8; ++i) v[i] = (base + i < n) ? in[base + i] : 0;
    int run = 0;
    #pragma unroll
    for (int i = 0; i < 8; ++i) { int c = v[i]; v[i] = run; run += c; }
    s[t] = run;
    __syncthreads();
    int x = run;
    for (int off = 1; off < 256; off <<= 1) {
        int y = (t >= off) ? s[t - off] : 0;
        __syncthreads();
        x += y; s[t] = x;
        __syncthreads();
    }
    const int texcl = x - run;
    if (t == 255) bsum[blockIdx.x] = x;
    #pragma unroll
    for (int i = 0; i < 8; ++i)
        if (base + i < n) out[base + i] = texcl + v[i];
}

__global__ void scan_bsums_kernel(int* bsum, int nb) {
    const int l = threadIdx.x;   // 64 threads
    if (nb <= 64) {
        int v = (l < nb) ? bsum[l] : 0;
        const int orig = v;
        for (int off = 1; off < 64; off <<= 1) {
            int y = __shfl_up(v, off, 64);
            if (l >= off) v += y;
        }
        if (l < nb) bsum[l] = v - orig;   // exclusive
    } else if (l == 0) {
        int run = 0;
        for (int b = 0; b < nb; ++b) { int tt = bsum[b]; bsum[b] = run; run += tt; }
    }
}

__global__ __launch_bounds__(256) void scan_add_kernel(int* __restrict__ offs,
                                                       const int* __restrict__ bsum,
                                                       int* __restrict__ cursor, int n) {
    const int base = blockIdx.x * 2048 + threadIdx.x * 8;
    const int add = bsum[blockIdx.x];
    #pragma unroll
    for (int i = 0; i < 8; ++i)
        if (base + i < n) { int v = offs[base + i] + add; offs[base + i] = v; cursor[base + i] = v; }
}

__global__ __launch_bounds__(256) void scatter_kernel(const int* __restrict__ ei,
                                                      int* __restrict__ cursor,
                                                      int* __restrict__ eids,
                                                      int2* __restrict__ sd, int nE) {
    int e = blockIdx.x * 256 + threadIdx.x;
    const int stride = gridDim.x * 256;
    for (; e < nE; e += stride) {
        const int s = ei[e];
        const int d = ei[nE + e];
        const int pos = atomicAdd(&cursor[d], 1);
        eids[pos] = e;
        sd[pos] = make_int2(s, d);
    }
}

// ---------------- Kernel B: node update + LayerNorm + GELU + residual ----------------
__global__ __launch_bounds__(256) void node_update_kernel(
    const float* __restrict__ nf,   // [N,64]
    const float* agg,               // [N,64] (may alias out)
    const float* __restrict__ W3,   // [128,64]
    const float* __restrict__ b3,   // [64]
    const float* __restrict__ lns,  // [64]
    const float* __restrict__ lnb,  // [64]
    float* out, int nN)
{
    __shared__ float sW3[128][64];
    __shared__ float sU[128][TN + 4];   // upd transposed [k][n]
    __shared__ float sP1[16][TN];
    __shared__ float sP2[16][TN];
    __shared__ float sMu[TN];
    __shared__ float sRs[TN];

    const int t = threadIdx.x;
    for (int i = t * 4; i < 128 * 64; i += 1024)
        *(float4*)((float*)sW3 + i) = *(const float4*)(W3 + i);

    const int lane = t & 63;
    const int w    = t >> 6;
    const int tb   = blockIdx.x * TN;
    const int node = tb + lane;
    const bool valid = node < nN;

    {
        const float* base = (w < 2) ? (nf  + (size_t)node * 64 + w * 32)
                                    : (agg + (size_t)node * 64 + (w - 2) * 32);
        const int kb = (w < 2) ? (w * 32) : (64 + (w - 2) * 32);
        #pragma unroll
        for (int q = 0; q < 8; ++q) {
            F4 v;
            v.v = valid ? *(const float4*)(base + q * 4) : make_float4(0.f, 0.f, 0.f, 0.f);
            #pragma unroll
            for (int j = 0; j < 4; ++j)
                sU[kb + q * 4 + j][lane] = v.f[j];
        }
    }

    const int n0 = (t & 15) * 4;
    const int c0 = (t >> 4) * 4;
    F4 b3v, sv, bv;
    b3v.v = *(const float4*)(b3  + c0);
    sv.v  = *(const float4*)(lns + c0);
    bv.v  = *(const float4*)(lnb + c0);
    __syncthreads();

    float acc[4][4] = {};
    #pragma unroll 8
    for (int k = 0; k < 128; ++k) {
        F4 xv, wv;
        xv.v = *(const float4*)&sU[k][n0];
        wv.v = *(const float4*)&sW3[k][c0];
        #pragma unroll
        for (int i = 0; i < 4; ++i)
            #pragma unroll
            for (int j = 0; j < 4; ++j)
                acc[i][j] = fmaf(xv.f[i], wv.f[j], acc[i][j]);
    }

    float h[4][4];
    #pragma unroll
    for (int i = 0; i < 4; ++i)
        #pragma unroll
        for (int j = 0; j < 4; ++j)
            h[i][j] = acc[i][j] + b3v.f[j];

    const int cg = t >> 4;
    #pragma unroll
    for (int i = 0; i < 4; ++i) {
        float s1 = h[i][0] + h[i][1] + h[i][2] + h[i][3];
        float s2 = h[i][0]*h[i][0] + h[i][1]*h[i][1] + h[i][2]*h[i][2] + h[i][3]*h[i][3];
        sP1[cg][n0 + i] = s1;
        sP2[cg][n0 + i] = s2;
    }
    __syncthreads();
    if (t < TN) {
        float m1 = 0.f, m2 = 0.f;
        #pragma unroll
        for (int g = 0; g < 16; ++g) { m1 += sP1[g][t]; m2 += sP2[g][t]; }
        float mu  = m1 * (1.f / 64.f);
        float var = m2 * (1.f / 64.f) - mu * mu;
        sMu[t] = mu;
        sRs[t] = rsqrtf(var + 1e-6f);
    }
    __syncthreads();

    #pragma unroll
    for (int i = 0; i < 4; ++i) {
        const int gnode = tb + n0 + i;
        const float mu = sMu[n0 + i];
        const float rs = sRs[n0 + i];
        if (gnode < nN) {
            #pragma unroll
            for (int j = 0; j < 4; ++j) {
                float xn = (h[i][j] - mu) * rs * sv.f[j] + bv.f[j];
                float r  = gelu_f(xn) + sU[c0 + j][n0 + i];
                out[(size_t)gnode * 64 + c0 + j] = r;
            }
        }
    }
}

extern "C" void kernel_launch(void* const* d_in, const int* in_sizes, int n_in,
                              void* d_out, int out_size, void* d_ws, size_t ws_size,
                              hipStream_t stream)
{
    const float* nf  = (const float*)d_in[0];
    const float* ef  = (const float*)d_in[1];
    const int*   ei  = (const int*)  d_in[2];
    const float* W1  = (const float*)d_in[3];
    const float* b1  = (const float*)d_in[4];
    const float* W2  = (const float*)d_in[5];
    const float* b2  = (const float*)d_in[6];
    const float* W3  = (const float*)d_in[7];
    const float* b3  = (const float*)d_in[8];
    const float* lns = (const float*)d_in[9];
    const float* lnb = (const float*)d_in[10];

    const int nN = in_sizes[0] / 64;
    const int nE = in_sizes[2] / 2;
    float* out = (float*)d_out;
    const int* dstArr = ei + nE;

    const int nTiles = (nE + TE - 1) / TE;
    const int gridA  = nTiles < 1024 ? nTiles : 1024;   // 4 blocks/CU (39.4KB LDS)
    const int gridB  = (nN + TN - 1) / TN;

    // ws layout: CSR arrays first (small), optional agg after
    char* ws = (char*)d_ws;
    size_t off = 0;
    auto take = [&](size_t bytes) { void* p = ws + off; off = (off + bytes + 255) & ~(size_t)255; return p; };
    int*  counts = (int*) take((size_t)nN * 4);
    int*  offs   = (int*) take((size_t)nN * 4);
    int*  cursor = (int*) take((size_t)nN * 4);
    int*  bsum   = (int*) take(4096);
    int*  eids   = (int*) take((size_t)nE * 4);
    int2* sd     = (int2*)take((size_t)nE * 8);
    const size_t csrEnd = off;
    float* aggw  = (float*)take((size_t)nN * 64 * 4);
    const size_t aggBytes = (size_t)nN * 64 * 4;

    if (ws_size >= csrEnd) {
        // ---- sorted/segmented path ----
        float* agg = (ws_size >= off) ? aggw : out;   // aliasing out is safe (block-local RAW)
        const int nb = (nN + 2047) / 2048;
        hipMemsetAsync(counts, 0, (size_t)nN * 4, stream);
        hipMemsetAsync(agg, 0, aggBytes, stream);
        hipLaunchKernelGGL(hist_kernel, dim3(2048), dim3(256), 0, stream, dstArr, counts, nE);
        hipLaunchKernelGGL(scan_local_kernel, dim3(nb), dim3(256), 0, stream, counts, offs, bsum, nN);
        hipLaunchKernelGGL(scan_bsums_kernel, dim3(1), dim3(64), 0, stream, bsum, nb);
        hipLaunchKernelGGL(scan_add_kernel, dim3(nb), dim3(256), 0, stream, offs, bsum, cursor, nN);
        hipLaunchKernelGGL(scatter_kernel, dim3(2048), dim3(256), 0, stream, ei, cursor, eids, sd, nE);
        hipLaunchKernelGGL(edge_mlp_kernel, dim3(gridA), dim3(256), 0, stream,
                           nf, ef, ei, eids, sd, W1, b1, W2, b2, agg, nE, nTiles);
        hipLaunchKernelGGL(node_update_kernel, dim3(gridB), dim3(256), 0, stream,
                           nf, agg, W3, b3, lns, lnb, out, nN);
    } else {
        // ---- fallback: per-edge atomics ----
        float* agg = (ws_size >= aggBytes) ? (float*)d_ws : out;
        hipMemsetAsync(agg, 0, aggBytes, stream);
        hipLaunchKernelGGL(edge_mlp_kernel, dim3(gridA), dim3(256), 0, stream,
                           nf, ef, ei, (const int*)nullptr, (const int2*)nullptr,
                           W1, b1, W2, b2, agg, nE, nTiles);
        hipLaunchKernelGGL(node_update_kernel, dim3(gridB), dim3(256), 0, stream,
                           nf, agg, W3, b3, lns, lnb, out, nN);
    }
}

// Round 7
// 427.261 us; speedup vs baseline: 2.6339x; 1.6104x over previous
//
#include <hip/hip_runtime.h>

#define TE 64      // edges per tile (kernel A)
#define TN 64      // nodes per tile (kernel B)

union F4 { float4 v; float f[4]; };

__device__ __forceinline__ float gelu_f(float x) {
    // jax.nn.gelu(approximate=True): 0.5*x*(1+tanh(sqrt(2/pi)*(x+0.044715*x^3)))
    const float c0 = 0.7978845608028654f;
    float z = c0 * (x + 0.044715f * x * x * x);
    float ez = __builtin_exp2f(z * 2.8853900817779268f);
    float th = 1.0f - 2.0f * __builtin_amdgcn_rcpf(ez + 1.0f);
    return 0.5f * x * (1.0f + th);
}

// barrier that does NOT drain vmcnt: own-wave LDS ops drained (lgkmcnt),
// global stores/atomics stay in flight across tiles.
__device__ __forceinline__ void barrier_lgkm() {
    asm volatile("s_waitcnt lgkmcnt(0)" ::: "memory");
    __builtin_amdgcn_s_barrier();
}

// ---------------- Kernel A: edge MLP (GEMM2 algebraically removed) ----------------
// sorted (eids!=null): per-tile segmented reduction of gelu1 into gSum.
//   np!=null: GEMM1 = ef@W1[64:80] + nodePart[src]  (16 k-iters)
//   np==null: GEMM1 = concat(nf,ef)@W1              (80 k-iters)
// fallback (eids==null): old path — full GEMM1 + GEMM2 + per-edge atomics.
__global__ __launch_bounds__(256, 4) void edge_mlp_kernel(
    const float* __restrict__ nf,   // [N,64]
    const float* __restrict__ ef,   // [E,16]
    const int*   __restrict__ ei,   // [2,E] int32
    const int*   __restrict__ eids, // [E] dst-sorted edge ids, or null
    const int2*  __restrict__ sd,   // [E] {src,dst} sorted, or null
    const float* __restrict__ np,   // [N,64] nodePart = nf@W1[0:64], or null
    const float* __restrict__ W1,   // [80,64]
    const float* __restrict__ b1,   // [64]
    const float* __restrict__ W2,   // [64,64] (fallback only)
    const float* __restrict__ b2,   // [64]    (fallback only)
    float*       agg,               // gSum[N,64] (sorted) or agg[N,64] (fallback); pre-zeroed
    int nE, int nTiles)
{
    __shared__ float sX[80][TE + 4];   // inputs transposed [k][e]
    __shared__ float sM[64][TE + 4];   // gelu(msg1) transposed [c][e]
    __shared__ int   sDst[TE];
    __shared__ int   sSrc[TE];

    const int t    = threadIdx.x;
    const int lane = t & 63;
    const int w    = t >> 6;          // wave id 0..3
    const int e0   = (t & 15) * 4;    // microtile edges
    const int c0   = (t >> 4) * 4;    // microtile channels
    const bool sorted = (eids != nullptr);
    const bool useNP  = (np != nullptr);
    F4 b1v;
    b1v.v = *(const float4*)(b1 + c0);

    for (int tile = blockIdx.x; tile < nTiles; tile += gridDim.x) {
        const int gbase = tile * TE;
        // ---- gather ----
        {
            const int idx = gbase + lane;
            const int ci = idx < nE ? idx : nE - 1;     // clamp (tail-safe)
            int ge, src, dstv;
            if (sorted) {
                ge = eids[ci];
                const int2 p = sd[ci];
                src  = p.x;
                dstv = (idx < nE) ? p.y : -1;           // sentinel for pad edges
            } else {
                ge   = ci;
                src  = ei[ge];
                dstv = (idx < nE) ? ei[nE + ge] : -1;
            }
            F4 ev;
            ev.v = *(const float4*)(ef + (size_t)ge * 16 + w * 4);
            if (useNP) {
                #pragma unroll
                for (int j = 0; j < 4; ++j)
                    sX[w * 4 + j][lane] = ev.f[j];      // ef rows 0..15
            } else {
                const float4* nrow = (const float4*)(nf + (size_t)src * 64);
                F4 a0, a1, a2, a3;
                a0.v = nrow[w * 4 + 0];
                a1.v = nrow[w * 4 + 1];
                a2.v = nrow[w * 4 + 2];
                a3.v = nrow[w * 4 + 3];
                const int kb = w * 16;
                #pragma unroll
                for (int j = 0; j < 4; ++j) {
                    sX[kb + 0  + j][lane] = a0.f[j];
                    sX[kb + 4  + j][lane] = a1.f[j];
                    sX[kb + 8  + j][lane] = a2.f[j];
                    sX[kb + 12 + j][lane] = a3.f[j];
                    sX[64 + w * 4 + j][lane] = ev.f[j];
                }
            }
            if (w == 0) sDst[lane] = dstv;
            if (w == 1) sSrc[lane] = src;
        }
        barrier_lgkm();

        // ---- GEMM1 ----
        float acc[4][4] = {};
        if (useNP) {
            #pragma unroll
            for (int k = 0; k < 16; ++k) {
                F4 xv, wv;
                xv.v = *(const float4*)&sX[k][e0];
                wv.v = *(const float4*)(W1 + (64 + k) * 64 + c0);
                #pragma unroll
                for (int i = 0; i < 4; ++i)
                    #pragma unroll
                    for (int j = 0; j < 4; ++j)
                        acc[i][j] = fmaf(xv.f[i], wv.f[j], acc[i][j]);
            }
            // add precomputed nodePart[src] rows
            #pragma unroll
            for (int i = 0; i < 4; ++i) {
                F4 npv;
                npv.v = *(const float4*)(np + (size_t)sSrc[e0 + i] * 64 + c0);
                #pragma unroll
                for (int j = 0; j < 4; ++j)
                    acc[i][j] += npv.f[j];
            }
        } else {
            #pragma unroll 8
            for (int k = 0; k < 80; ++k) {
                F4 xv, wv;
                xv.v = *(const float4*)&sX[k][e0];
                wv.v = *(const float4*)(W1 + k * 64 + c0);
                #pragma unroll
                for (int i = 0; i < 4; ++i)
                    #pragma unroll
                    for (int j = 0; j < 4; ++j)
                        acc[i][j] = fmaf(xv.f[i], wv.f[j], acc[i][j]);
            }
        }

        // gelu + write transposed gelu1
        #pragma unroll
        for (int j = 0; j < 4; ++j) {
            F4 col;
            #pragma unroll
            for (int i = 0; i < 4; ++i)
                col.f[i] = gelu_f(acc[i][j] + b1v.f[j]);
            *(float4*)&sM[c0 + j][e0] = col.v;
        }
        barrier_lgkm();

        if (sorted) {
            // ---- segmented reduction of gelu1 along sorted-edge axis ----
            const int c  = t >> 2;
            const int q  = t & 3;
            const int cb = q * 16;
            int   cur = -1;
            float run = 0.f;
            #pragma unroll
            for (int s = 0; s < 4; ++s) {
                F4 rv;
                rv.v = *(const float4*)&sM[c][cb + s * 4];
                #pragma unroll
                for (int j = 0; j < 4; ++j) {
                    const int d = sDst[cb + s * 4 + j];
                    if (d != cur) {
                        if (cur >= 0)
                            __hip_atomic_fetch_add(agg + (size_t)cur * 64 + c, run,
                                                   __ATOMIC_RELAXED, __HIP_MEMORY_SCOPE_AGENT);
                        cur = d;
                        run = 0.f;
                    }
                    if (d >= 0) run += rv.f[j];
                }
            }
            if (cur >= 0)
                __hip_atomic_fetch_add(agg + (size_t)cur * 64 + c, run,
                                       __ATOMIC_RELAXED, __HIP_MEMORY_SCOPE_AGENT);
            barrier_lgkm();   // protect sM/sDst/sSrc before next gather
        } else {
            // ---- fallback: GEMM2 + per-edge atomic scatter ----
            float acc2[4][4] = {};
            #pragma unroll 8
            for (int k = 0; k < 64; ++k) {
                F4 xv, wv;
                xv.v = *(const float4*)&sM[k][e0];
                wv.v = *(const float4*)(W2 + k * 64 + c0);
                #pragma unroll
                for (int i = 0; i < 4; ++i)
                    #pragma unroll
                    for (int j = 0; j < 4; ++j)
                        acc2[i][j] = fmaf(xv.f[i], wv.f[j], acc2[i][j]);
            }
            F4 b2v;
            b2v.v = *(const float4*)(b2 + c0);
            #pragma unroll
            for (int i = 0; i < 4; ++i) {
                if (gbase + e0 + i < nE) {
                    float* arow = agg + (size_t)sDst[e0 + i] * 64 + c0;
                    #pragma unroll
                    for (int j = 0; j < 4; ++j)
                        __hip_atomic_fetch_add(arow + j, acc2[i][j] + b2v.f[j],
                                               __ATOMIC_RELAXED, __HIP_MEMORY_SCOPE_AGENT);
                }
            }
            barrier_lgkm();
        }
    }
}

// ---------------- nodePart = nf @ W1[0:64,:] (no bias) ----------------
__global__ __launch_bounds__(256) void node_part_kernel(
    const float* __restrict__ nf, const float* __restrict__ W1,
    float* __restrict__ np, int nN)
{
    __shared__ float sU[64][TN + 4];
    const int t = threadIdx.x;
    const int lane = t & 63;
    const int w = t >> 6;
    const int tb = blockIdx.x * TN;
    const int node = (tb + lane < nN) ? tb + lane : nN - 1;
    {
        const float4* nrow = (const float4*)(nf + (size_t)node * 64);
        F4 a0, a1, a2, a3;
        a0.v = nrow[w * 4 + 0];
        a1.v = nrow[w * 4 + 1];
        a2.v = nrow[w * 4 + 2];
        a3.v = nrow[w * 4 + 3];
        const int kb = w * 16;
        #pragma unroll
        for (int j = 0; j < 4; ++j) {
            sU[kb + 0  + j][lane] = a0.f[j];
            sU[kb + 4  + j][lane] = a1.f[j];
            sU[kb + 8  + j][lane] = a2.f[j];
            sU[kb + 12 + j][lane] = a3.f[j];
        }
    }
    barrier_lgkm();
    const int n0 = (t & 15) * 4;
    const int c0 = (t >> 4) * 4;
    float acc[4][4] = {};
    #pragma unroll 8
    for (int k = 0; k < 64; ++k) {
        F4 xv, wv;
        xv.v = *(const float4*)&sU[k][n0];
        wv.v = *(const float4*)(W1 + k * 64 + c0);
        #pragma unroll
        for (int i = 0; i < 4; ++i)
            #pragma unroll
            for (int j = 0; j < 4; ++j)
                acc[i][j] = fmaf(xv.f[i], wv.f[j], acc[i][j]);
    }
    #pragma unroll
    for (int i = 0; i < 4; ++i) {
        const int gnode = tb + n0 + i;
        if (gnode < nN) {
            F4 o;
            #pragma unroll
            for (int j = 0; j < 4; ++j) o.f[j] = acc[i][j];
            *(float4*)(np + (size_t)gnode * 64 + c0) = o.v;
        }
    }
}

// ---------------- W23 = W2 @ W3[64:128,:], b2w = b2 @ W3[64:128,:] ----------------
__global__ void prep_w23_kernel(const float* __restrict__ W2, const float* __restrict__ W3,
                                const float* __restrict__ b2,
                                float* __restrict__ W23, float* __restrict__ b2w)
{
    const int t = threadIdx.x;           // 256
    const int c = t & 63;
    const int kg = t >> 6;
    for (int k = kg * 16; k < kg * 16 + 16; ++k) {
        float s = 0.f;
        for (int m = 0; m < 64; ++m)
            s = fmaf(W2[k * 64 + m], W3[(64 + m) * 64 + c], s);
        W23[k * 64 + c] = s;
    }
    if (t < 64) {
        float s = 0.f;
        for (int m = 0; m < 64; ++m)
            s = fmaf(b2[m], W3[(64 + m) * 64 + t], s);
        b2w[t] = s;
    }
}

// ---------------- CSR build ----------------
__global__ __launch_bounds__(256) void hist_kernel(const int* __restrict__ dst,
                                                   int* __restrict__ counts, int nE) {
    int e = blockIdx.x * 256 + threadIdx.x;
    const int stride = gridDim.x * 256;
    for (; e < nE; e += stride)
        atomicAdd(&counts[dst[e]], 1);
}

__global__ __launch_bounds__(256) void scan_local_kernel(const int* __restrict__ in,
                                                         int* __restrict__ out,
                                                         int* __restrict__ bsum, int n) {
    __shared__ int s[256];
    const int t = threadIdx.x;
    const int base = blockIdx.x * 2048 + t * 8;
    int v[8];
    #pragma unroll
    for (int i = 0; i < 8; ++i) v[i] = (base + i < n) ? in[base + i] : 0;
    int run = 0;
    #pragma unroll
    for (int i = 0; i < 8; ++i) { int c = v[i]; v[i] = run; run += c; }
    s[t] = run;
    __syncthreads();
    int x = run;
    for (int off = 1; off < 256; off <<= 1) {
        int y = (t >= off) ? s[t - off] : 0;
        __syncthreads();
        x += y; s[t] = x;
        __syncthreads();
    }
    const int texcl = x - run;
    if (t == 255) bsum[blockIdx.x] = x;
    #pragma unroll
    for (int i = 0; i < 8; ++i)
        if (base + i < n) out[base + i] = texcl + v[i];
}

__global__ void scan_bsums_kernel(int* bsum, int nb) {
    const int l = threadIdx.x;   // 64 threads
    if (nb <= 64) {
        int v = (l < nb) ? bsum[l] : 0;
        const int orig = v;
        for (int off = 1; off < 64; off <<= 1) {
            int y = __shfl_up(v, off, 64);
            if (l >= off) v += y;
        }
        if (l < nb) bsum[l] = v - orig;   // exclusive
    } else if (l == 0) {
        int run = 0;
        for (int b = 0; b < nb; ++b) { int tt = bsum[b]; bsum[b] = run; run += tt; }
    }
}

__global__ __launch_bounds__(256) void scan_add_kernel(int* __restrict__ offs,
                                                       const int* __restrict__ bsum,
                                                       int* __restrict__ cursor, int n) {
    const int base = blockIdx.x * 2048 + threadIdx.x * 8;
    const int add = bsum[blockIdx.x];
    #pragma unroll
    for (int i = 0; i < 8; ++i)
        if (base + i < n) { int v = offs[base + i] + add; offs[base + i] = v; cursor[base + i] = v; }
}

__global__ __launch_bounds__(256) void scatter_kernel(const int* __restrict__ ei,
                                                      int* __restrict__ cursor,
                                                      int* __restrict__ eids,
                                                      int2* __restrict__ sd, int nE) {
    int e = blockIdx.x * 256 + threadIdx.x;
    const int stride = gridDim.x * 256;
    for (; e < nE; e += stride) {
        const int s = ei[e];
        const int d = ei[nE + e];
        const int pos = atomicAdd(&cursor[d], 1);
        eids[pos] = e;
        sd[pos] = make_int2(s, d);
    }
}

// ---------------- Kernel B: node update + LayerNorm + GELU + residual ----------------
// h = nf@sW[0:64] + gsum@sW[64:128] + b3 (+ cnt*cvec when provided); then LN,GELU,residual.
__global__ __launch_bounds__(256) void node_update_kernel(
    const float* __restrict__ nf,    // [N,64]
    const float* gsum,               // [N,64] (may alias out)
    const float* __restrict__ W3,    // rows 0..63 weight source
    const float* __restrict__ wB,    // rows 64..127 weight source (W23 or W3+4096)
    const float* __restrict__ b3,    // [64]
    const float* __restrict__ cvec,  // b2w[64] or null
    const int*   __restrict__ counts,// [N] or null
    const float* __restrict__ lns,   // [64]
    const float* __restrict__ lnb,   // [64]
    float* out, int nN)
{
    __shared__ float sW3[128][64];
    __shared__ float sU[128][TN + 4];
    __shared__ float sP1[16][TN];
    __shared__ float sP2[16][TN];
    __shared__ float sMu[TN];
    __shared__ float sRs[TN];

    const int t = threadIdx.x;
    for (int i = t * 4; i < 64 * 64; i += 1024)
        *(float4*)((float*)sW3 + i) = *(const float4*)(W3 + i);
    for (int i = t * 4; i < 64 * 64; i += 1024)
        *(float4*)((float*)sW3 + 4096 + i) = *(const float4*)(wB + i);

    const int lane = t & 63;
    const int w    = t >> 6;
    const int tb   = blockIdx.x * TN;
    const int node = tb + lane;
    const bool valid = node < nN;

    {
        const float* base = (w < 2) ? (nf   + (size_t)node * 64 + w * 32)
                                    : (gsum + (size_t)node * 64 + (w - 2) * 32);
        const int kb = (w < 2) ? (w * 32) : (64 + (w - 2) * 32);
        #pragma unroll
        for (int q = 0; q < 8; ++q) {
            F4 v;
            v.v = valid ? *(const float4*)(base + q * 4) : make_float4(0.f, 0.f, 0.f, 0.f);
            #pragma unroll
            for (int j = 0; j < 4; ++j)
                sU[kb + q * 4 + j][lane] = v.f[j];
        }
    }

    const int n0 = (t & 15) * 4;
    const int c0 = (t >> 4) * 4;
    F4 b3v, sv, bv, cv;
    b3v.v = *(const float4*)(b3  + c0);
    sv.v  = *(const float4*)(lns + c0);
    bv.v  = *(const float4*)(lnb + c0);
    if (cvec) cv.v = *(const float4*)(cvec + c0);
    __syncthreads();

    float acc[4][4] = {};
    #pragma unroll 8
    for (int k = 0; k < 128; ++k) {
        F4 xv, wv;
        xv.v = *(const float4*)&sU[k][n0];
        wv.v = *(const float4*)&sW3[k][c0];
        #pragma unroll
        for (int i = 0; i < 4; ++i)
            #pragma unroll
            for (int j = 0; j < 4; ++j)
                acc[i][j] = fmaf(xv.f[i], wv.f[j], acc[i][j]);
    }

    float h[4][4];
    #pragma unroll
    for (int i = 0; i < 4; ++i) {
        float cf = 0.f;
        if (counts) {
            const int gnode = tb + n0 + i;
            cf = (float)counts[gnode < nN ? gnode : nN - 1];
        }
        #pragma unroll
        for (int j = 0; j < 4; ++j) {
            float v = acc[i][j] + b3v.f[j];
            if (cvec) v = fmaf(cf, cv.f[j], v);
            h[i][j] = v;
        }
    }

    const int cg = t >> 4;
    #pragma unroll
    for (int i = 0; i < 4; ++i) {
        float s1 = h[i][0] + h[i][1] + h[i][2] + h[i][3];
        float s2 = h[i][0]*h[i][0] + h[i][1]*h[i][1] + h[i][2]*h[i][2] + h[i][3]*h[i][3];
        sP1[cg][n0 + i] = s1;
        sP2[cg][n0 + i] = s2;
    }
    __syncthreads();
    if (t < TN) {
        float m1 = 0.f, m2 = 0.f;
        #pragma unroll
        for (int g = 0; g < 16; ++g) { m1 += sP1[g][t]; m2 += sP2[g][t]; }
        float mu  = m1 * (1.f / 64.f);
        float var = m2 * (1.f / 64.f) - mu * mu;
        sMu[t] = mu;
        sRs[t] = rsqrtf(var + 1e-6f);
    }
    __syncthreads();

    #pragma unroll
    for (int i = 0; i < 4; ++i) {
        const int gnode = tb + n0 + i;
        const float mu = sMu[n0 + i];
        const float rs = sRs[n0 + i];
        if (gnode < nN) {
            #pragma unroll
            for (int j = 0; j < 4; ++j) {
                float xn = (h[i][j] - mu) * rs * sv.f[j] + bv.f[j];
                float r  = gelu_f(xn) + sU[c0 + j][n0 + i];
                out[(size_t)gnode * 64 + c0 + j] = r;
            }
        }
    }
}

extern "C" void kernel_launch(void* const* d_in, const int* in_sizes, int n_in,
                              void* d_out, int out_size, void* d_ws, size_t ws_size,
                              hipStream_t stream)
{
    const float* nf  = (const float*)d_in[0];
    const float* ef  = (const float*)d_in[1];
    const int*   ei  = (const int*)  d_in[2];
    const float* W1  = (const float*)d_in[3];
    const float* b1  = (const float*)d_in[4];
    const float* W2  = (const float*)d_in[5];
    const float* b2  = (const float*)d_in[6];
    const float* W3  = (const float*)d_in[7];
    const float* b3  = (const float*)d_in[8];
    const float* lns = (const float*)d_in[9];
    const float* lnb = (const float*)d_in[10];

    const int nN = in_sizes[0] / 64;
    const int nE = in_sizes[2] / 2;
    float* out = (float*)d_out;
    const int* dstArr = ei + nE;

    const int nTiles = (nE + TE - 1) / TE;
    const int gridA  = nTiles < 1024 ? nTiles : 1024;   // 4 blocks/CU
    const int gridB  = (nN + TN - 1) / TN;

    // ws layout: CSR + folded weights (small) -> nodePart -> gSum
    char* ws = (char*)d_ws;
    size_t off = 0;
    auto take = [&](size_t bytes) { void* p = ws + off; off = (off + bytes + 255) & ~(size_t)255; return p; };
    int*   counts = (int*)  take((size_t)nN * 4);
    int*   offs   = (int*)  take((size_t)nN * 4);
    int*   cursor = (int*)  take((size_t)nN * 4);
    int*   bsum   = (int*)  take(4096);
    int*   eids   = (int*)  take((size_t)nE * 4);
    int2*  sd     = (int2*) take((size_t)nE * 8);
    float* W23    = (float*)take(64 * 64 * 4);
    float* b2w    = (float*)take(64 * 4);
    const size_t tier1End = off;
    float* npart  = (float*)take((size_t)nN * 64 * 4);
    const size_t tier2End = off;
    float* gsumw  = (float*)take((size_t)nN * 64 * 4);
    const size_t tier3End = off;
    const size_t aggBytes = (size_t)nN * 64 * 4;

    if (ws_size >= tier1End) {
        const bool useNP = (ws_size >= tier2End);
        float* gsum = (ws_size >= tier3End) ? gsumw : out;  // aliasing out is safe (block-local RAW)
        const int nb = (nN + 2047) / 2048;
        hipMemsetAsync(counts, 0, (size_t)nN * 4, stream);
        hipMemsetAsync(gsum, 0, aggBytes, stream);
        hipLaunchKernelGGL(hist_kernel, dim3(2048), dim3(256), 0, stream, dstArr, counts, nE);
        hipLaunchKernelGGL(scan_local_kernel, dim3(nb), dim3(256), 0, stream, counts, offs, bsum, nN);
        hipLaunchKernelGGL(scan_bsums_kernel, dim3(1), dim3(64), 0, stream, bsum, nb);
        hipLaunchKernelGGL(scan_add_kernel, dim3(nb), dim3(256), 0, stream, offs, bsum, cursor, nN);
        hipLaunchKernelGGL(scatter_kernel, dim3(2048), dim3(256), 0, stream, ei, cursor, eids, sd, nE);
        hipLaunchKernelGGL(prep_w23_kernel, dim3(1), dim3(256), 0, stream, W2, W3, b2, W23, b2w);
        if (useNP)
            hipLaunchKernelGGL(node_part_kernel, dim3(gridB), dim3(256), 0, stream, nf, W1, npart, nN);
        hipLaunchKernelGGL(edge_mlp_kernel, dim3(gridA), dim3(256), 0, stream,
                           nf, ef, ei, eids, sd, useNP ? npart : (const float*)nullptr,
                           W1, b1, W2, b2, gsum, nE, nTiles);
        hipLaunchKernelGGL(node_update_kernel, dim3(gridB), dim3(256), 0, stream,
                           nf, gsum, W3, W23, b3, b2w, counts, lns, lnb, out, nN);
    } else {
        // fallback: old per-edge-atomic path
        float* agg = (ws_size >= aggBytes) ? (float*)d_ws : out;
        hipMemsetAsync(agg, 0, aggBytes, stream);
        hipLaunchKernelGGL(edge_mlp_kernel, dim3(gridA), dim3(256), 0, stream,
                           nf, ef, ei, (const int*)nullptr, (const int2*)nullptr, (const float*)nullptr,
                           W1, b1, W2, b2, agg, nE, nTiles);
        hipLaunchKernelGGL(node_update_kernel, dim3(gridB), dim3(256), 0, stream,
                           nf, agg, W3, W3 + 64 * 64, b3, (const float*)nullptr, (const int*)nullptr,
                           lns, lnb, out, nN);
    }
}